// Round 15
// baseline (89.362 us; speedup 1.0000x reference)
//
#include <hip/hip_runtime.h>

// LogicConv3d: B=4, C=3, H=W=D=32, K=32, S=16 leaves, tree depth 4 (31 LUT nodes).
// Out: (B, K, 30, 30, 30) = 3,456,000 fp32.
//
// R14 = R13 (fp16 d-shifted copies in d_ws, fused L0-2 fp16 eval, no slab)
// but 4 positions/thread instead of 8. Rationale: whole kernel was only ~7.7k
// waves (~1.5 occupancy-fills) — ramp/drain + per-wave dependent latency
// dominate; R6 vs R5 already showed 8-od is SLOWER than 4-od on an identical
// structure. Now 864k threads = 15.4k waves = 60 waves/CU of work.
//  - od0 = gq*4 (0..28): every leaf gather is ONE 8B-aligned dwordx2 (gq=7
//    reads od 28..31 from the zero-padded shifted copies, stores od 28,29).
//  - acc 16 VGPR + small transients -> __launch_bounds__(256,6).

#define B_  4
#define C_  3
#define H_  32
#define W_  32
#define D_  32
#define K_  32
#define S_  16
#define TPB 256
#define NX  393216   // B*C*H*W*D
#define CHWD (C_ * H_ * W_ * D_)

typedef float    v4fv __attribute__((ext_vector_type(4)));
typedef _Float16 h4   __attribute__((ext_vector_type(4), aligned(8)));
typedef float    f4a  __attribute__((ext_vector_type(4), aligned(4)));
typedef float    f2a  __attribute__((ext_vector_type(2), aligned(4)));

__device__ __forceinline__ v4fv cvt4(h4 h) {
    v4fv r;
    #pragma unroll
    for (int i = 0; i < 4; ++i) r[i] = (float)h[i];
    return r;
}

__device__ __forceinline__ h4 lut4h(h4 a, h4 b, _Float16 l0, _Float16 d1,
                                    _Float16 d2, _Float16 d3) {
    // E = l0 + a*d2 + b*d1 + (a*b)*d3 == fma(b, fma(a,d3,d1), fma(a,d2,l0))
    const h4 t0 = a * d2 + l0;
    const h4 t1 = a * d3 + d1;
    return b * t1 + t0;              // 6 v_pk_fma_f16 per call (4 halves)
}

__device__ __forceinline__ v4fv lut4f(v4fv a, v4fv b, float l0, float d1,
                                      float d2, float d3) {
    const v4fv t0 = a * d2 + l0;
    const v4fv t1 = a * d3 + d1;
    return b * t1 + t0;
}

__global__ __launch_bounds__(TPB) void prepass(const float* __restrict__ x,
                                               _Float16* __restrict__ y) {
    const int i = blockIdx.x * TPB + threadIdx.x;   // 0..NX-1
    const int d = i & 31;
    const float v0 = x[i];
    const float v1 = (d < 31) ? x[i + 1] : 0.f;     // shifted copies; tails feed
    const float v2 = (d < 30) ? x[i + 2] : 0.f;     // only dropped od 30/31
    y[i]          = (_Float16)v0;
    y[NX + i]     = (_Float16)v1;
    y[2 * NX + i] = (_Float16)v2;
}

__global__ __launch_bounds__(TPB, 6) void logic_conv3d(
    const _Float16* __restrict__ y,
    const int*      __restrict__ kc,
    const float*    __restrict__ w0,
    const float*    __restrict__ w1,
    const float*    __restrict__ w2,
    const float*    __restrict__ w3,
    const float*    __restrict__ w4,
    float*          __restrict__ out)
{
    __shared__ float4 s_lut[31];                     // fp32 (l0,d1,d2,d3) per node
    __shared__ __align__(8) _Float16 s_luth[24][4];  // fp16 copy, nodes 0..23
    __shared__ int s_lb[32];                         // leaf base in fp16-y coords

    const int bk  = blockIdx.x;      // b*K + k
    const int oh  = blockIdx.y;      // 0..29
    const int b   = bk >> 5;
    const int k   = bk & 31;
    const int tid = threadIdx.x;

    // ---- per-block setup: 31 softmax->LUT (delta form) + 32 leaf bases ----
    if (tid < 31) {
        const float* wp; int ln;
        if      (tid < 16) { wp = w0; ln = tid;      }
        else if (tid < 24) { wp = w1; ln = tid - 16; }
        else if (tid < 28) { wp = w2; ln = tid - 24; }
        else if (tid < 30) { wp = w3; ln = tid - 28; }
        else               { wp = w4; ln = 0;        }
        const float* wrow = wp + (ln * K_ + k) * 16;
        float lg[16];
        float m = -1e30f;
        #pragma unroll
        for (int g = 0; g < 16; ++g) { lg[g] = wrow[g]; m = fmaxf(m, lg[g]); }
        float z = 0.f;
        #pragma unroll
        for (int g = 0; g < 16; ++g) { lg[g] = __expf(lg[g] - m); z += lg[g]; }
        const float inv = 1.0f / z;
        float l0 = 0.f, l1 = 0.f, l2 = 0.f, l3 = 0.f;
        #pragma unroll
        for (int g = 0; g < 16; ++g) {
            float p = lg[g] * inv;           // GATES[g,t] = (g>>t)&1, t = 2*a+b
            if (g & 1) l0 += p;
            if (g & 2) l1 += p;
            if (g & 4) l2 += p;
            if (g & 8) l3 += p;
        }
        const float d1 = l1 - l0, d2 = l2 - l0, d3 = (l3 - l2) - (l1 - l0);
        s_lut[tid] = make_float4(l0, d1, d2, d3);
        if (tid < 24) {                      // fp16 copy for levels 0-1
            s_luth[tid][0] = (_Float16)l0;
            s_luth[tid][1] = (_Float16)d1;
            s_luth[tid][2] = (_Float16)d2;
            s_luth[tid][3] = (_Float16)d3;
        }
    } else if (tid >= 32 && tid < 64) {
        const int idx  = tid - 32;           // tree*16 + s
        const int tree = idx >> 4;
        const int s    = idx & 15;
        const int off  = ((tree * K_ + k) * S_ + s) * 4;  // kc (2,K,S,4) = (h,w,d,c)
        const int h = kc[off + 0], w = kc[off + 1], d = kc[off + 2], c = kc[off + 3];
        // copy d, spatial base multiple of 32 halves -> gathers stay 8B-aligned
        s_lb[idx] = d * NX + ((c * H_ + h) * W_ + w) * D_;
    }
    __syncthreads();

    // block-uniform leaf bases -> SGPRs (8 aligned b128 + readfirstlane)
    int sAB[32];
    #pragma unroll
    for (int i = 0; i < 8; ++i) {
        const int4 q = *(const int4*)&s_lb[i * 4];
        sAB[i * 4 + 0] = __builtin_amdgcn_readfirstlane(q.x);
        sAB[i * 4 + 1] = __builtin_amdgcn_readfirstlane(q.y);
        sAB[i * 4 + 2] = __builtin_amdgcn_readfirstlane(q.z);
        sAB[i * 4 + 3] = __builtin_amdgcn_readfirstlane(q.w);
    }

    // thread -> (ow, quad of consecutive od); lanes 0-7 cover one 64B d-row
    const int gq  = tid & 7;                 // 0..7
    const int ow  = tid >> 3;                // 0..31 (>=30 inactive)
    const int od0 = gq << 2;                 // 0,4,...,28 (gq=7: od 30,31 dropped)

    if (ow < 30) {
        const int voff = b * CHWD + oh * (W_ * D_) + ow * D_ + od0;
        const _Float16* yp = y + voff;

        // ---- fused levels 0+1+2: 4 leaves + 2 L1-nodes -> one L2 node ----
        v4fv v2acc[4];
        #pragma unroll
        for (int q = 0; q < 4; ++q) {
            const int s0 = 4 * q, s1 = 4 * q + 1, s2 = 4 * q + 2, s3 = 4 * q + 3;
            const h4 A0 = *(const h4*)(yp + sAB[s0]);
            const h4 B0 = *(const h4*)(yp + sAB[16 + s0]);
            const h4 A1 = *(const h4*)(yp + sAB[s1]);
            const h4 B1 = *(const h4*)(yp + sAB[16 + s1]);
            const _Float16* L0 = s_luth[s0];
            const _Float16* L1 = s_luth[s1];
            const h4 t0 = lut4h(A0, B0, L0[0], L0[1], L0[2], L0[3]);
            const h4 t1 = lut4h(A1, B1, L1[0], L1[1], L1[2], L1[3]);
            const _Float16* N0 = s_luth[16 + 2 * q];
            const h4 va = lut4h(t0, t1, N0[0], N0[1], N0[2], N0[3]);
            const h4 A2 = *(const h4*)(yp + sAB[s2]);
            const h4 B2 = *(const h4*)(yp + sAB[16 + s2]);
            const h4 A3 = *(const h4*)(yp + sAB[s3]);
            const h4 B3 = *(const h4*)(yp + sAB[16 + s3]);
            const _Float16* L2 = s_luth[s2];
            const _Float16* L3 = s_luth[s3];
            const h4 t2 = lut4h(A2, B2, L2[0], L2[1], L2[2], L2[3]);
            const h4 t3 = lut4h(A3, B3, L3[0], L3[1], L3[2], L3[3]);
            const _Float16* N1 = s_luth[17 + 2 * q];
            const h4 vb = lut4h(t2, t3, N1[0], N1[1], N1[2], N1[3]);
            const float4 M = s_lut[24 + q];
            v2acc[q] = lut4f(cvt4(va), cvt4(vb), M.x, M.y, M.z, M.w);
        }

        // ---- levels 3,4 (fp32): nodes 28,29 then 30 ----
        const float4 P0 = s_lut[28];
        const float4 P1 = s_lut[29];
        const v4fv u0 = lut4f(v2acc[0], v2acc[1], P0.x, P0.y, P0.z, P0.w);
        const v4fv u1 = lut4f(v2acc[2], v2acc[3], P1.x, P1.y, P1.z, P1.w);
        const float4 Pr = s_lut[30];
        const v4fv res = lut4f(u0, u1, Pr.x, Pr.y, Pr.z, Pr.w);

        // store: full quad for gq<7; od 28,29 only for gq==7
        float* outp = out + (size_t)bk * 27000 + oh * 900 + ow * 30 + od0;
        if (gq < 7) {
            f4a r4; r4[0] = res[0]; r4[1] = res[1]; r4[2] = res[2]; r4[3] = res[3];
            *(f4a*)outp = r4;
        } else {
            f2a r2; r2[0] = res[0]; r2[1] = res[1];
            *(f2a*)outp = r2;
        }
    }
}

extern "C" void kernel_launch(void* const* d_in, const int* in_sizes, int n_in,
                              void* d_out, int out_size, void* d_ws, size_t ws_size,
                              hipStream_t stream) {
    const float* x  = (const float*)d_in[0];
    const int*   kc = (const int*)d_in[1];
    const float* w0 = (const float*)d_in[2];
    const float* w1 = (const float*)d_in[3];
    const float* w2 = (const float*)d_in[4];
    const float* w3 = (const float*)d_in[5];
    const float* w4 = (const float*)d_in[6];
    float* out = (float*)d_out;
    _Float16* y = (_Float16*)d_ws;           // 3*NX halves = 2.36 MB

    prepass<<<NX / TPB, TPB, 0, stream>>>(x, y);
    dim3 grid(B_ * K_, 30);                  // (bk, oh) = 3840 blocks
    logic_conv3d<<<grid, TPB, 0, stream>>>(y, kc, w0, w1, w2, w3, w4, out);
}